// Round 10
// baseline (168.179 us; speedup 1.0000x reference)
//
#include <hip/hip_runtime.h>
#include <stdint.h>
#include <stddef.h>

#define EMB 768
#define SEQ 4096
#define NH 12
#define DH 64
#define LOG2E 1.44269504f
#define NSP 4
#define SPLEN (SEQ / NSP)            // 1024 kv per split
#define KVB 32
#define NBLK (NH * 32 * NSP)         // 1536 blocks: 12 heads x 32 qtiles(128) x 4 splits

typedef __attribute__((ext_vector_type(8))) short short8;
typedef __attribute__((ext_vector_type(4))) float f32x4;
typedef __attribute__((ext_vector_type(16))) float f32x16;
typedef __attribute__((ext_vector_type(2))) unsigned int uint32x2;

// ---------- helpers ----------
static __device__ __forceinline__ unsigned short f2bf(float f) {
  union { float f; uint32_t u; } v; v.f = f;
  uint32_t u = v.u;
  return (unsigned short)((u + 0x7FFFu + ((u >> 16) & 1u)) >> 16);
}
static __device__ __forceinline__ float bf2f(unsigned short s) {
  union { uint32_t u; float f; } v; v.u = ((uint32_t)s) << 16;
  return v.f;
}

static __device__ __forceinline__ void gl_lds16(const void* g, void* l) {
  __builtin_amdgcn_global_load_lds(
      (const __attribute__((address_space(1))) uint32_t*)g,
      (__attribute__((address_space(3))) uint32_t*)l, 16, 0, 0);
}
static __device__ __forceinline__ void gl_lds4(const void* g, void* l) {
  __builtin_amdgcn_global_load_lds(
      (const __attribute__((address_space(1))) uint32_t*)g,
      (__attribute__((address_space(3))) uint32_t*)l, 4, 0, 0);
}

// cross-half combine via the permlane32_swap BUILTIN (asm with duplicated
// "+v" operands coalesces registers -> degenerate swap; round-4 failure).
static __device__ __forceinline__ float xhalf_max(float v) {
  union { float f; unsigned int u; } x; x.f = v;
  uint32x2 r = __builtin_amdgcn_permlane32_swap(x.u, x.u, false, false);
  union { unsigned int u; float f; } a, b; a.u = r[0]; b.u = r[1];
  return fmaxf(a.f, b.f);
}
static __device__ __forceinline__ float xhalf_sum(float v) {
  union { float f; unsigned int u; } x; x.f = v;
  uint32x2 r = __builtin_amdgcn_permlane32_swap(x.u, x.u, false, false);
  union { unsigned int u; float f; } a, b; a.u = r[0]; b.u = r[1];
  return a.f + b.f;
}

// ---------- fused prep: fp32->bf16 of x + 4 weights, and mask bias ----------
// mb2 = -80000 * (1 - mask) == (exp2-domain additive bias) / sc2; attn
// C-initializes the QK accumulator with it and scales once after MFMA.
__global__ void prep_kernel(const float* __restrict__ x, const float* __restrict__ mask,
                            const float* __restrict__ Wq, const float* __restrict__ Wk,
                            const float* __restrict__ Wv, const float* __restrict__ Wo,
                            unsigned short* __restrict__ xb, unsigned short* __restrict__ wqb,
                            unsigned short* __restrict__ wkb, unsigned short* __restrict__ wvb,
                            unsigned short* __restrict__ wob, float* __restrict__ mb2) {
  const int y = blockIdx.y;
  if (y == 5) {
    int i = blockIdx.x * 256 + threadIdx.x;
    if (i < SEQ) mb2[i] = -80000.f * (1.f - mask[i]);
    return;
  }
  const float* in = y == 0 ? x : y == 1 ? Wq : y == 2 ? Wk : y == 3 ? Wv : Wo;
  unsigned short* out = y == 0 ? xb : y == 1 ? wqb : y == 2 ? wkb : y == 3 ? wvb : wob;
  const int n = (y == 0) ? SEQ * EMB : EMB * EMB;
  int stride = gridDim.x * blockDim.x * 4;
  for (int i = (blockIdx.x * blockDim.x + threadIdx.x) * 4; i < n; i += stride) {
    float4 v = *reinterpret_cast<const float4*>(in + i);
    ushort4 o;
    o.x = f2bf(v.x); o.y = f2bf(v.y); o.z = f2bf(v.z); o.w = f2bf(v.w);
    *reinterpret_cast<ushort4*>(out + i) = o;
  }
}

// ---------- GEMM core: C[M][N] = A[M][K] * W[N][K]^T + bias ----------
template <int OUT_F32>
static __device__ __forceinline__ void gemm128(
    const unsigned short* __restrict__ A, const unsigned short* __restrict__ W,
    const float* __restrict__ bias, void* __restrict__ Cout,
    int M, int N, int K, int bm, int bn) {
  __shared__ unsigned short Alds[128 * 64];
  __shared__ unsigned short Blds[128 * 64];
  const int t = threadIdx.x;
  const int lane = t & 63;
  const int wave = t >> 6;
  const int wr = wave >> 1, wc = wave & 1;
  const int lm = lane & 15, lg = lane >> 4;

  f32x4 acc[4][4];
#pragma unroll
  for (int i = 0; i < 4; ++i)
#pragma unroll
    for (int j = 0; j < 4; ++j) acc[i][j] = (f32x4){0.f, 0.f, 0.f, 0.f};

  const int srow = t >> 3;
  const int scsw = (t & 7) * 16;

  const int nK = K >> 6;
  for (int kt = 0; kt < nK; ++kt) {
    const int k0 = kt << 6;
#pragma unroll
    for (int i = 0; i < 4; ++i) {
      int row = i * 32 + srow;
      int cb = scsw ^ ((row & 7) << 4);
      gl_lds16(A + (size_t)(bm * 128 + row) * K + k0 + (cb >> 1),
               (char*)Alds + i * 4096 + t * 16);
      gl_lds16(W + (size_t)(bn * 128 + row) * K + k0 + (cb >> 1),
               (char*)Blds + i * 4096 + t * 16);
    }
    __syncthreads();
#pragma unroll
    for (int kk = 0; kk < 2; ++kk) {
      short8 af[4], bfr[4];
#pragma unroll
      for (int i = 0; i < 4; ++i) {
        int rowa = wr * 64 + i * 16 + lm;
        int cba = (kk * 64 + lg * 16) ^ ((rowa & 7) << 4);
        af[i] = *reinterpret_cast<const short8*>((const char*)Alds + rowa * 128 + cba);
        int rowb = wc * 64 + i * 16 + lm;
        int cbb = (kk * 64 + lg * 16) ^ ((rowb & 7) << 4);
        bfr[i] = *reinterpret_cast<const short8*>((const char*)Blds + rowb * 128 + cbb);
      }
#pragma unroll
      for (int i = 0; i < 4; ++i)
#pragma unroll
        for (int j = 0; j < 4; ++j)
          acc[i][j] = __builtin_amdgcn_mfma_f32_16x16x32_bf16(af[i], bfr[j], acc[i][j], 0, 0, 0);
    }
    __syncthreads();
  }
#pragma unroll
  for (int i = 0; i < 4; ++i) {
    int row0 = bm * 128 + wr * 64 + i * 16 + lg * 4;
#pragma unroll
    for (int j = 0; j < 4; ++j) {
      int col = bn * 128 + wc * 64 + j * 16 + lm;
      float b = bias[col];
#pragma unroll
      for (int r = 0; r < 4; ++r) {
        float v = acc[i][j][r] + b;
        if (OUT_F32)
          ((float*)Cout)[(size_t)(row0 + r) * N + col] = v;
        else
          ((unsigned short*)Cout)[(size_t)(row0 + r) * N + col] = f2bf(v);
      }
    }
  }
}

__global__ __launch_bounds__(256, 2) void gemm_wo(
    const unsigned short* __restrict__ A, const unsigned short* __restrict__ W,
    const float* __restrict__ bias, float* __restrict__ C) {
  gemm128<1>(A, W, bias, C, SEQ, EMB, EMB, blockIdx.x, blockIdx.y);
}

__global__ __launch_bounds__(256, 2) void qkv_gemm(
    const unsigned short* __restrict__ A,
    const unsigned short* __restrict__ W0, const unsigned short* __restrict__ W1,
    const unsigned short* __restrict__ W2,
    const float* __restrict__ b0, const float* __restrict__ b1, const float* __restrict__ b2,
    unsigned short* __restrict__ O0, unsigned short* __restrict__ O1,
    unsigned short* __restrict__ O2) {
  const int z = blockIdx.z;
  const unsigned short* W = z == 0 ? W0 : z == 1 ? W1 : W2;
  const float* bias = z == 0 ? b0 : z == 1 ? b1 : b2;
  unsigned short* O = z == 0 ? O0 : z == 1 ? O1 : O2;
  gemm128<0>(A, W, bias, O, SEQ, EMB, EMB, blockIdx.x, blockIdx.y);
}

// ---------- V transpose: V[SEQ][EMB] -> Vt[EMB][SEQ] (bf16) ----------
__global__ void transpose_kernel(const unsigned short* __restrict__ in,
                                 unsigned short* __restrict__ out) {
  __shared__ unsigned short tile[32][33];
  int tx = threadIdx.x, ty = threadIdx.y;   // 32 x 8
  int e0 = blockIdx.x * 32, s0 = blockIdx.y * 32;
#pragma unroll
  for (int i = 0; i < 4; ++i)
    tile[ty + i * 8][tx] = in[(size_t)(s0 + ty + i * 8) * EMB + e0 + tx];
  __syncthreads();
#pragma unroll
  for (int i = 0; i < 4; ++i)
    out[(size_t)(e0 + ty + i * 8) * SEQ + s0 + tx] = tile[tx][ty + i * 8];
}

// ---------- flash attention: split-4, KVB=32, 6 blocks/CU ----------
// 1536 blocks = 12 heads x 32 qtiles(128 rows) x 4 kv-splits = exactly
// 6 blocks/CU (24 waves/CU = 6/SIMD, 2x round-9 occupancy). LDS 17.2 KB:
// K dbuf 2x4KB ([32 kv][64 d], 128B rows, swz (row&7)<<4), V dbuf 2x4KB
// ([32][64] two d-rows packed per 128B row, same swizzle), mask, bcs.
// Partials stored NORMALIZED in bf16 (halves merge traffic vs f32).
__global__ __launch_bounds__(256, 6) void attn_kernel(
    const unsigned short* __restrict__ Q, const unsigned short* __restrict__ Kb,
    const unsigned short* __restrict__ Vt, const float* __restrict__ mb2,
    unsigned short* __restrict__ opart, float* __restrict__ mpart,
    float* __restrict__ lpart) {
  __shared__ unsigned short Klds[2][KVB * DH];
  __shared__ unsigned short Vlds[2][KVB * DH];
  __shared__ __align__(16) float msk[2][KVB];
  __shared__ __align__(16) float bcs[4][32];

  const int t = threadIdx.x;
  const int lane = t & 63;
  const int wave = t >> 6;
  const int o = blockIdx.x;
  const int wg = (o & 7) * (NBLK / 8) + (o >> 3);  // bijective: 1536 % 8 == 0
  const int head = wg >> 7;                        // 128 blocks per head
  const int rem = wg & 127;
  const int qb = rem >> 2;                         // q-tile of 128 rows
  const int sp = rem & 3;
  const int q0 = qb * 128 + wave * 32;
  const int kvb0 = sp * SPLEN;
  const int lm = lane & 31;
  const int h = lane >> 5;

  // Q B-fragments (col = q = lm, k-octet = d = 16ks + 8h .. +8)
  short8 qf[4];
#pragma unroll
  for (int ks = 0; ks < 4; ++ks)
    qf[ks] = *reinterpret_cast<const short8*>(
        Q + (size_t)(q0 + lm) * EMB + head * DH + ks * 16 + h * 8);

  f32x16 oacc[2];
#pragma unroll
  for (int n = 0; n < 2; ++n)
#pragma unroll
    for (int r = 0; r < 16; ++r) oacc[n][r] = 0.f;
  float mrun = -3.0e38f, lrun = 0.f;

  const int srow = t >> 3;          // 0..31
  const int so16 = t & 7;

  // 3 vmem per wave per STAGE: 1 K gl_lds16 + 1 V gl_lds16 + 1 mask gl_lds4
  auto STAGE = [&](int buf, int kt2) {
    const int kv0 = kvb0 + kt2 * KVB;
    // K: [kv row][64 d] 128B rows; inverse-swizzled source
    int kcb = (so16 * 16) ^ ((srow & 7) << 4);
    gl_lds16(Kb + (size_t)(kv0 + srow) * EMB + head * DH + (kcb >> 1),
             (char*)Klds + buf * 4096 + t * 16);
    // V: row = d>>1; logical o16' = o16 ^ (row&7); d = 2*row + (o16'>>2);
    // kv slot = (o16'&3)*8 elements
    int vo16p = so16 ^ (srow & 7);
    int vd = 2 * srow + (vo16p >> 2);
    gl_lds16(Vt + (size_t)(head * DH + vd) * SEQ + kv0 + (vo16p & 3) * 8,
             (char*)Vlds + buf * 4096 + t * 16);
    if (lane < KVB) gl_lds4(mb2 + kv0 + lane, &msk[buf][0]);
  };

  constexpr int NT = SPLEN / KVB;   // 32
  STAGE(0, 0);
  __syncthreads();

  for (int kt = 0; kt < NT; ++kt) {
    const int buf = kt & 1;
    if (kt + 1 < NT) STAGE(buf ^ 1, kt + 1);

    // QK^T swapped: C[kv][q]; ACC INIT = mask bias / sc2 (from staged LDS)
    f32x16 s;
#pragma unroll
    for (int a = 0; a < 4; ++a) {
      f32x4 m = *reinterpret_cast<const f32x4*>(&msk[buf][a * 8 + h * 4]);
#pragma unroll
      for (int i = 0; i < 4; ++i) s[a * 4 + i] = m[i];
    }

    __builtin_amdgcn_s_setprio(1);
#pragma unroll
    for (int ks = 0; ks < 4; ++ks) {
      int cb = (ks * 32 + h * 16) ^ ((lm & 7) << 4);
      short8 kf = *reinterpret_cast<const short8*>(
          (const char*)Klds + buf * 4096 + lm * 128 + cb);
      s = __builtin_amdgcn_mfma_f32_32x32x16_bf16(kf, qf[ks], s, 0, 0, 0);
    }
    __builtin_amdgcn_s_setprio(0);

    // single scale pass (mask already inside acc)
    const float sc2 = 0.125f * LOG2E;
#pragma unroll
    for (int r = 0; r < 16; ++r) s[r] *= sc2;

    // row max: tree over 16 lane-local values + cross-half permlane
    float red[8];
#pragma unroll
    for (int r = 0; r < 8; ++r) red[r] = fmaxf(s[r], s[r + 8]);
#pragma unroll
    for (int off = 4; off >= 1; off >>= 1)
#pragma unroll
      for (int r = 0; r < off; ++r) red[r] = fmaxf(red[r], red[r + off]);
    float pm = xhalf_max(red[0]);

    // defer-max: rescale O only when max grows past threshold
    if (!__all(pm <= mrun + 8.0f)) {
      float mnew = fmaxf(mrun, pm);
      float sf = __builtin_amdgcn_exp2f(mrun - mnew);
      mrun = mnew;
      lrun *= sf;
      bcs[wave][lm] = sf;
      f32x16 svv;
#pragma unroll
      for (int a = 0; a < 4; ++a) {
        f32x4 sv = *reinterpret_cast<const f32x4*>(&bcs[wave][a * 8 + h * 4]);
#pragma unroll
        for (int i = 0; i < 4; ++i) svv[a * 4 + i] = sv[i];
      }
      oacc[0] = oacc[0] * svv;
      oacc[1] = oacc[1] * svv;
    }

    // P = exp2(s - m)
#pragma unroll
    for (int r = 0; r < 16; ++r)
      s[r] = __builtin_amdgcn_exp2f(s[r] - mrun);

    // row sum
    float rs[8];
#pragma unroll
    for (int r = 0; r < 8; ++r) rs[r] = s[r] + s[r + 8];
#pragma unroll
    for (int off = 4; off >= 1; off >>= 1)
#pragma unroll
      for (int r = 0; r < off; ++r) rs[r] += rs[r + off];
    lrun += xhalf_sum(rs[0]);

    // P -> bf16 A-fragments (T12: cvt_pk + permlane32_swap)
    uint32_t r0[4], r1[4];
#pragma unroll
    for (int a = 0; a < 4; ++a) {
      asm("v_cvt_pk_bf16_f32 %0, %1, %2" : "=v"(r0[a]) : "v"(s[4 * a]), "v"(s[4 * a + 1]));
      asm("v_cvt_pk_bf16_f32 %0, %1, %2" : "=v"(r1[a]) : "v"(s[4 * a + 2]), "v"(s[4 * a + 3]));
    }
    short8 pa[2];
#pragma unroll
    for (int ksl = 0; ksl < 2; ++ksl) {
      uint32x2 w0 = __builtin_amdgcn_permlane32_swap(r0[2 * ksl], r0[2 * ksl + 1], false, false);
      uint32x2 w1 = __builtin_amdgcn_permlane32_swap(r1[2 * ksl], r1[2 * ksl + 1], false, false);
      union { short8 s8; uint32_t u[4]; } pk;
      pk.u[0] = w0[0]; pk.u[1] = w1[0]; pk.u[2] = w0[1]; pk.u[3] = w1[1];
      pa[ksl] = pk.s8;
    }

    // PV: oacc[n] += P * V   (V packed two d-rows per 128B LDS row)
    __builtin_amdgcn_s_setprio(1);
#pragma unroll
    for (int n = 0; n < 2; ++n)
#pragma unroll
      for (int ks = 0; ks < 2; ++ks) {
        int d = n * 32 + lm;
        int row = d >> 1;
        int o16p = (d & 1) * 4 + ks * 2 + h;
        int cb = ((o16p ^ (row & 7)) << 4);
        short8 vf = *reinterpret_cast<const short8*>(
            (const char*)Vlds + buf * 4096 + row * 128 + cb);
        oacc[n] = __builtin_amdgcn_mfma_f32_32x32x16_bf16(pa[ks], vf, oacc[n], 0, 0, 0);
      }
    __builtin_amdgcn_s_setprio(0);

    __syncthreads();
  }

  // epilogue: normalize by local l, store bf16 partial + (m, l)
  bcs[wave][lm] = __builtin_amdgcn_rcpf(lrun);
  f32x16 lv;
#pragma unroll
  for (int a = 0; a < 4; ++a) {
    f32x4 sv = *reinterpret_cast<const f32x4*>(&bcs[wave][a * 8 + h * 4]);
#pragma unroll
    for (int i = 0; i < 4; ++i) lv[a * 4 + i] = sv[i];
  }
  unsigned short* ob = opart + ((size_t)(sp * NH + head) * SEQ + q0) * 64;
#pragma unroll
  for (int n = 0; n < 2; ++n)
#pragma unroll
    for (int r = 0; r < 16; ++r) {
      int crow = (r & 3) + 8 * (r >> 2) + 4 * h;
      ob[crow * 64 + n * 32 + lm] = f2bf(oacc[n][r] * lv[r]);
    }
  if (h == 0) {
    mpart[(size_t)(sp * NH + head) * SEQ + q0 + lm] = mrun;
    lpart[(size_t)(sp * NH + head) * SEQ + q0 + lm] = lrun;
  }
}

// ---------- merge the four KV-splits (bf16 normalized partials) ----------
__global__ void merge_kernel(const unsigned short* __restrict__ opart,
                             const float* __restrict__ mpart,
                             const float* __restrict__ lpart,
                             unsigned short* __restrict__ Ab) {
  int tid = blockIdx.x * 256 + threadIdx.x;   // 786432 total
  int dv = tid & 15;
  int rq = tid >> 4;
  int head = rq >> 12;
  int q = rq & 4095;
  size_t base = (size_t)head * SEQ + q;
  const size_t str = (size_t)NH * SEQ;

  float m[NSP], l[NSP];
#pragma unroll
  for (int sp = 0; sp < NSP; ++sp) {
    m[sp] = mpart[base + sp * str];
    l[sp] = lpart[base + sp * str];
  }
  float mx = fmaxf(fmaxf(m[0], m[1]), fmaxf(m[2], m[3]));
  float w[NSP], denom = 0.f;
#pragma unroll
  for (int sp = 0; sp < NSP; ++sp) {
    w[sp] = __builtin_amdgcn_exp2f(m[sp] - mx) * l[sp];
    denom += w[sp];
  }
  float rd = 1.0f / denom;

  float acc0 = 0.f, acc1 = 0.f, acc2 = 0.f, acc3 = 0.f;
#pragma unroll
  for (int sp = 0; sp < NSP; ++sp) {
    float c = w[sp] * rd;
    ushort4 ov = *reinterpret_cast<const ushort4*>(
        opart + (base + sp * str) * 64 + dv * 4);
    acc0 += c * bf2f(ov.x);
    acc1 += c * bf2f(ov.y);
    acc2 += c * bf2f(ov.z);
    acc3 += c * bf2f(ov.w);
  }
  ushort4 r;
  r.x = f2bf(acc0); r.y = f2bf(acc1); r.z = f2bf(acc2); r.w = f2bf(acc3);
  *reinterpret_cast<ushort4*>(Ab + (size_t)q * EMB + head * DH + dv * 4) = r;
}

// ---------- launch ----------
extern "C" void kernel_launch(void* const* d_in, const int* in_sizes, int n_in,
                              void* d_out, int out_size, void* d_ws, size_t ws_size,
                              hipStream_t stream) {
  const float* x    = (const float*)d_in[0];
  const float* mask = (const float*)d_in[1];
  const float* Wq   = (const float*)d_in[2];
  const float* bq   = (const float*)d_in[3];
  const float* Wk   = (const float*)d_in[4];
  const float* bk   = (const float*)d_in[5];
  const float* Wv   = (const float*)d_in[6];
  const float* bv   = (const float*)d_in[7];
  const float* Wo   = (const float*)d_in[8];
  const float* bo   = (const float*)d_in[9];
  float* out = (float*)d_out;

  char* ws = (char*)d_ws;
  const size_t SZ_X = (size_t)SEQ * EMB * 2;
  const size_t SZ_W = (size_t)EMB * EMB * 2;
  unsigned short* xb  = (unsigned short*)(ws);
  unsigned short* wqb = (unsigned short*)(ws + SZ_X);
  unsigned short* wkb = (unsigned short*)(ws + SZ_X + SZ_W);
  unsigned short* wvb = (unsigned short*)(ws + SZ_X + 2 * SZ_W);
  unsigned short* wob = (unsigned short*)(ws + SZ_X + 3 * SZ_W);
  unsigned short* Qb  = (unsigned short*)(ws + SZ_X + 4 * SZ_W);
  unsigned short* Kbuf= (unsigned short*)(ws + 2 * SZ_X + 4 * SZ_W);
  unsigned short* Vb  = (unsigned short*)(ws + 3 * SZ_X + 4 * SZ_W);
  unsigned short* Vtb = (unsigned short*)(ws + 4 * SZ_X + 4 * SZ_W);
  unsigned short* Ab  = (unsigned short*)(ws + 5 * SZ_X + 4 * SZ_W);
  size_t off = 6 * SZ_X + 4 * SZ_W;
  float* mb2            = (float*)(ws + off);          off += (size_t)SEQ * 4;
  unsigned short* opart = (unsigned short*)(ws + off); off += (size_t)NSP * NH * SEQ * 64 * 2;
  float* mpart          = (float*)(ws + off);          off += (size_t)NSP * NH * SEQ * 4;
  float* lpart          = (float*)(ws + off);

  prep_kernel<<<dim3(192, 6), 256, 0, stream>>>(
      x, mask, Wq, Wk, Wv, Wo, xb, wqb, wkb, wvb, wob, mb2);

  qkv_gemm<<<dim3(SEQ / 128, EMB / 128, 3), 256, 0, stream>>>(
      xb, wqb, wkb, wvb, bq, bk, bv, Qb, Kbuf, Vb);

  transpose_kernel<<<dim3(EMB / 32, SEQ / 32), dim3(32, 8), 0, stream>>>(Vb, Vtb);

  attn_kernel<<<NBLK, 256, 0, stream>>>(Qb, Kbuf, Vtb, mb2, opart, mpart, lpart);
  merge_kernel<<<3072, 256, 0, stream>>>(opart, mpart, lpart, Ab);

  gemm_wo<<<dim3(SEQ / 128, EMB / 128), 256, 0, stream>>>(Ab, wob, bo, out);
}

// Round 12
// 142.942 us; speedup vs baseline: 1.1766x; 1.1766x over previous
//
#include <hip/hip_runtime.h>
#include <stdint.h>
#include <stddef.h>

#define EMB 768
#define SEQ 4096
#define NH 12
#define DH 64
#define LOG2E 1.44269504f
#define NSP 4
#define SPLEN (SEQ / NSP)            // 1024 kv per split
#define KVB 32
#define NBLK (NH * 32 * NSP)         // 1536 blocks: 12 heads x 32 qtiles(128) x 4 splits

typedef __attribute__((ext_vector_type(8))) short short8;
typedef __attribute__((ext_vector_type(4))) float f32x4;
typedef __attribute__((ext_vector_type(16))) float f32x16;
typedef __attribute__((ext_vector_type(2))) unsigned int uint32x2;

// ---------- helpers ----------
static __device__ __forceinline__ unsigned short f2bf(float f) {
  union { float f; uint32_t u; } v; v.f = f;
  uint32_t u = v.u;
  return (unsigned short)((u + 0x7FFFu + ((u >> 16) & 1u)) >> 16);
}
static __device__ __forceinline__ float bf2f(unsigned short s) {
  union { uint32_t u; float f; } v; v.u = ((uint32_t)s) << 16;
  return v.f;
}

static __device__ __forceinline__ void gl_lds16(const void* g, void* l) {
  __builtin_amdgcn_global_load_lds(
      (const __attribute__((address_space(1))) uint32_t*)g,
      (__attribute__((address_space(3))) uint32_t*)l, 16, 0, 0);
}
static __device__ __forceinline__ void gl_lds4(const void* g, void* l) {
  __builtin_amdgcn_global_load_lds(
      (const __attribute__((address_space(1))) uint32_t*)g,
      (__attribute__((address_space(3))) uint32_t*)l, 4, 0, 0);
}

// cross-half combine via the permlane32_swap BUILTIN (asm with duplicated
// "+v" operands coalesces registers -> degenerate swap; round-4 failure).
static __device__ __forceinline__ float xhalf_max(float v) {
  union { float f; unsigned int u; } x; x.f = v;
  uint32x2 r = __builtin_amdgcn_permlane32_swap(x.u, x.u, false, false);
  union { unsigned int u; float f; } a, b; a.u = r[0]; b.u = r[1];
  return fmaxf(a.f, b.f);
}
static __device__ __forceinline__ float xhalf_sum(float v) {
  union { float f; unsigned int u; } x; x.f = v;
  uint32x2 r = __builtin_amdgcn_permlane32_swap(x.u, x.u, false, false);
  union { unsigned int u; float f; } a, b; a.u = r[0]; b.u = r[1];
  return a.f + b.f;
}

// ---------- fused prep: fp32->bf16 of x + 4 weights, and mask bias ----------
// mb2 = -80000 * (1 - mask) == (exp2-domain additive bias) / sc2; attn
// C-initializes the QK accumulator with it and scales once after MFMA.
__global__ void prep_kernel(const float* __restrict__ x, const float* __restrict__ mask,
                            const float* __restrict__ Wq, const float* __restrict__ Wk,
                            const float* __restrict__ Wv, const float* __restrict__ Wo,
                            unsigned short* __restrict__ xb, unsigned short* __restrict__ wqb,
                            unsigned short* __restrict__ wkb, unsigned short* __restrict__ wvb,
                            unsigned short* __restrict__ wob, float* __restrict__ mb2) {
  const int y = blockIdx.y;
  if (y == 5) {
    int i = blockIdx.x * 256 + threadIdx.x;
    if (i < SEQ) mb2[i] = -80000.f * (1.f - mask[i]);
    return;
  }
  const float* in = y == 0 ? x : y == 1 ? Wq : y == 2 ? Wk : y == 3 ? Wv : Wo;
  unsigned short* out = y == 0 ? xb : y == 1 ? wqb : y == 2 ? wkb : y == 3 ? wvb : wob;
  const int n = (y == 0) ? SEQ * EMB : EMB * EMB;
  int stride = gridDim.x * blockDim.x * 4;
  for (int i = (blockIdx.x * blockDim.x + threadIdx.x) * 4; i < n; i += stride) {
    float4 v = *reinterpret_cast<const float4*>(in + i);
    ushort4 o;
    o.x = f2bf(v.x); o.y = f2bf(v.y); o.z = f2bf(v.z); o.w = f2bf(v.w);
    *reinterpret_cast<ushort4*>(out + i) = o;
  }
}

// ---------- GEMM core: C[M][N] = A[M][K] * W[N][K]^T + bias ----------
template <int OUT_F32>
static __device__ __forceinline__ void gemm128(
    const unsigned short* __restrict__ A, const unsigned short* __restrict__ W,
    const float* __restrict__ bias, void* __restrict__ Cout,
    int M, int N, int K, int bm, int bn) {
  __shared__ unsigned short Alds[128 * 64];
  __shared__ unsigned short Blds[128 * 64];
  const int t = threadIdx.x;
  const int lane = t & 63;
  const int wave = t >> 6;
  const int wr = wave >> 1, wc = wave & 1;
  const int lm = lane & 15, lg = lane >> 4;

  f32x4 acc[4][4];
#pragma unroll
  for (int i = 0; i < 4; ++i)
#pragma unroll
    for (int j = 0; j < 4; ++j) acc[i][j] = (f32x4){0.f, 0.f, 0.f, 0.f};

  const int srow = t >> 3;
  const int scsw = (t & 7) * 16;

  const int nK = K >> 6;
  for (int kt = 0; kt < nK; ++kt) {
    const int k0 = kt << 6;
#pragma unroll
    for (int i = 0; i < 4; ++i) {
      int row = i * 32 + srow;
      int cb = scsw ^ ((row & 7) << 4);
      gl_lds16(A + (size_t)(bm * 128 + row) * K + k0 + (cb >> 1),
               (char*)Alds + i * 4096 + t * 16);
      gl_lds16(W + (size_t)(bn * 128 + row) * K + k0 + (cb >> 1),
               (char*)Blds + i * 4096 + t * 16);
    }
    __syncthreads();
#pragma unroll
    for (int kk = 0; kk < 2; ++kk) {
      short8 af[4], bfr[4];
#pragma unroll
      for (int i = 0; i < 4; ++i) {
        int rowa = wr * 64 + i * 16 + lm;
        int cba = (kk * 64 + lg * 16) ^ ((rowa & 7) << 4);
        af[i] = *reinterpret_cast<const short8*>((const char*)Alds + rowa * 128 + cba);
        int rowb = wc * 64 + i * 16 + lm;
        int cbb = (kk * 64 + lg * 16) ^ ((rowb & 7) << 4);
        bfr[i] = *reinterpret_cast<const short8*>((const char*)Blds + rowb * 128 + cbb);
      }
#pragma unroll
      for (int i = 0; i < 4; ++i)
#pragma unroll
        for (int j = 0; j < 4; ++j)
          acc[i][j] = __builtin_amdgcn_mfma_f32_16x16x32_bf16(af[i], bfr[j], acc[i][j], 0, 0, 0);
    }
    __syncthreads();
  }
#pragma unroll
  for (int i = 0; i < 4; ++i) {
    int row0 = bm * 128 + wr * 64 + i * 16 + lg * 4;
#pragma unroll
    for (int j = 0; j < 4; ++j) {
      int col = bn * 128 + wc * 64 + j * 16 + lm;
      float b = bias[col];
#pragma unroll
      for (int r = 0; r < 4; ++r) {
        float v = acc[i][j][r] + b;
        if (OUT_F32)
          ((float*)Cout)[(size_t)(row0 + r) * N + col] = v;
        else
          ((unsigned short*)Cout)[(size_t)(row0 + r) * N + col] = f2bf(v);
      }
    }
  }
}

__global__ __launch_bounds__(256, 2) void gemm_wo(
    const unsigned short* __restrict__ A, const unsigned short* __restrict__ W,
    const float* __restrict__ bias, float* __restrict__ C) {
  gemm128<1>(A, W, bias, C, SEQ, EMB, EMB, blockIdx.x, blockIdx.y);
}

__global__ __launch_bounds__(256, 2) void qkv_gemm(
    const unsigned short* __restrict__ A,
    const unsigned short* __restrict__ W0, const unsigned short* __restrict__ W1,
    const unsigned short* __restrict__ W2,
    const float* __restrict__ b0, const float* __restrict__ b1, const float* __restrict__ b2,
    unsigned short* __restrict__ O0, unsigned short* __restrict__ O1,
    unsigned short* __restrict__ O2) {
  const int z = blockIdx.z;
  const unsigned short* W = z == 0 ? W0 : z == 1 ? W1 : W2;
  const float* bias = z == 0 ? b0 : z == 1 ? b1 : b2;
  unsigned short* O = z == 0 ? O0 : z == 1 ? O1 : O2;
  gemm128<0>(A, W, bias, O, SEQ, EMB, EMB, blockIdx.x, blockIdx.y);
}

// ---------- V transpose: V[SEQ][EMB] -> Vt[EMB][SEQ] (bf16) ----------
__global__ void transpose_kernel(const unsigned short* __restrict__ in,
                                 unsigned short* __restrict__ out) {
  __shared__ unsigned short tile[32][33];
  int tx = threadIdx.x, ty = threadIdx.y;   // 32 x 8
  int e0 = blockIdx.x * 32, s0 = blockIdx.y * 32;
#pragma unroll
  for (int i = 0; i < 4; ++i)
    tile[ty + i * 8][tx] = in[(size_t)(s0 + ty + i * 8) * EMB + e0 + tx];
  __syncthreads();
#pragma unroll
  for (int i = 0; i < 4; ++i)
    out[(size_t)(e0 + ty + i * 8) * SEQ + s0 + tx] = tile[tx][ty + i * 8];
}

// ---------- flash attention: split-4, KVB=32, no-spill occupancy ----------
// 1536 blocks = 12 heads x 32 qtiles(128 rows) x 4 kv-splits. LDS 17.4 KB.
// launch_bounds(256,4): VGPR cap 128 -- round-10's (256,6) capped at ~85 and
// SPILLED (VGPR=40, +42MB scratch writes, +74MB scratch reads per dispatch).
// Natural usage ~90-100 still gives 5 waves/SIMD resident by HW allocation.
__global__ __launch_bounds__(256, 4) void attn_kernel(
    const unsigned short* __restrict__ Q, const unsigned short* __restrict__ Kb,
    const unsigned short* __restrict__ Vt, const float* __restrict__ mb2,
    unsigned short* __restrict__ opart, float* __restrict__ mpart,
    float* __restrict__ lpart) {
  __shared__ unsigned short Klds[2][KVB * DH];
  __shared__ unsigned short Vlds[2][KVB * DH];
  __shared__ __align__(16) float msk[2][KVB];
  __shared__ __align__(16) float bcs[4][32];

  const int t = threadIdx.x;
  const int lane = t & 63;
  const int wave = t >> 6;
  const int o = blockIdx.x;
  const int wg = (o & 7) * (NBLK / 8) + (o >> 3);  // bijective: 1536 % 8 == 0
  const int head = wg >> 7;                        // 128 blocks per head
  const int rem = wg & 127;
  const int qb = rem >> 2;                         // q-tile of 128 rows
  const int sp = rem & 3;
  const int q0 = qb * 128 + wave * 32;
  const int kvb0 = sp * SPLEN;
  const int lm = lane & 31;
  const int h = lane >> 5;

  // Q B-fragments (col = q = lm, k-octet = d = 16ks + 8h .. +8)
  short8 qf[4];
#pragma unroll
  for (int ks = 0; ks < 4; ++ks)
    qf[ks] = *reinterpret_cast<const short8*>(
        Q + (size_t)(q0 + lm) * EMB + head * DH + ks * 16 + h * 8);

  f32x16 oacc[2];
#pragma unroll
  for (int n = 0; n < 2; ++n)
#pragma unroll
    for (int r = 0; r < 16; ++r) oacc[n][r] = 0.f;
  float mrun = -3.0e38f, lrun = 0.f;

  const int srow = t >> 3;          // 0..31
  const int so16 = t & 7;

  // 3 vmem per wave per STAGE: 1 K gl_lds16 + 1 V gl_lds16 + 1 mask gl_lds4
  auto STAGE = [&](int buf, int kt2) {
    const int kv0 = kvb0 + kt2 * KVB;
    // K: [kv row][64 d] 128B rows; inverse-swizzled source
    int kcb = (so16 * 16) ^ ((srow & 7) << 4);
    gl_lds16(Kb + (size_t)(kv0 + srow) * EMB + head * DH + (kcb >> 1),
             (char*)Klds + buf * 4096 + t * 16);
    // V: row = d>>1; logical o16' = o16 ^ (row&7); d = 2*row + (o16'>>2);
    // kv slot = (o16'&3)*8 elements
    int vo16p = so16 ^ (srow & 7);
    int vd = 2 * srow + (vo16p >> 2);
    gl_lds16(Vt + (size_t)(head * DH + vd) * SEQ + kv0 + (vo16p & 3) * 8,
             (char*)Vlds + buf * 4096 + t * 16);
    if (lane < KVB) gl_lds4(mb2 + kv0 + lane, &msk[buf][0]);
  };

  constexpr int NT = SPLEN / KVB;   // 32
  STAGE(0, 0);
  __syncthreads();

  for (int kt = 0; kt < NT; ++kt) {
    const int buf = kt & 1;
    if (kt + 1 < NT) STAGE(buf ^ 1, kt + 1);

    // QK^T swapped: C[kv][q]; ACC INIT = mask bias / sc2 (from staged LDS)
    f32x16 s;
#pragma unroll
    for (int a = 0; a < 4; ++a) {
      f32x4 m = *reinterpret_cast<const f32x4*>(&msk[buf][a * 8 + h * 4]);
#pragma unroll
      for (int i = 0; i < 4; ++i) s[a * 4 + i] = m[i];
    }

    __builtin_amdgcn_s_setprio(1);
#pragma unroll
    for (int ks = 0; ks < 4; ++ks) {
      int cb = (ks * 32 + h * 16) ^ ((lm & 7) << 4);
      short8 kf = *reinterpret_cast<const short8*>(
          (const char*)Klds + buf * 4096 + lm * 128 + cb);
      s = __builtin_amdgcn_mfma_f32_32x32x16_bf16(kf, qf[ks], s, 0, 0, 0);
    }
    __builtin_amdgcn_s_setprio(0);

    // single scale pass (mask already inside acc)
    const float sc2 = 0.125f * LOG2E;
#pragma unroll
    for (int r = 0; r < 16; ++r) s[r] *= sc2;

    // row max: tree over 16 lane-local values + cross-half permlane
    float red[8];
#pragma unroll
    for (int r = 0; r < 8; ++r) red[r] = fmaxf(s[r], s[r + 8]);
#pragma unroll
    for (int off = 4; off >= 1; off >>= 1)
#pragma unroll
      for (int r = 0; r < off; ++r) red[r] = fmaxf(red[r], red[r + off]);
    float pm = xhalf_max(red[0]);

    // defer-max: rescale O only when max grows past threshold
    if (!__all(pm <= mrun + 8.0f)) {
      float mnew = fmaxf(mrun, pm);
      float sf = __builtin_amdgcn_exp2f(mrun - mnew);
      mrun = mnew;
      lrun *= sf;
      bcs[wave][lm] = sf;
      f32x16 svv;
#pragma unroll
      for (int a = 0; a < 4; ++a) {
        f32x4 sv = *reinterpret_cast<const f32x4*>(&bcs[wave][a * 8 + h * 4]);
#pragma unroll
        for (int i = 0; i < 4; ++i) svv[a * 4 + i] = sv[i];
      }
      oacc[0] = oacc[0] * svv;
      oacc[1] = oacc[1] * svv;
    }

    // P = exp2(s - m)
#pragma unroll
    for (int r = 0; r < 16; ++r)
      s[r] = __builtin_amdgcn_exp2f(s[r] - mrun);

    // row sum
    float rs[8];
#pragma unroll
    for (int r = 0; r < 8; ++r) rs[r] = s[r] + s[r + 8];
#pragma unroll
    for (int off = 4; off >= 1; off >>= 1)
#pragma unroll
      for (int r = 0; r < off; ++r) rs[r] += rs[r + off];
    lrun += xhalf_sum(rs[0]);

    // P -> bf16 A-fragments (T12: cvt_pk + permlane32_swap)
    uint32_t r0[4], r1[4];
#pragma unroll
    for (int a = 0; a < 4; ++a) {
      asm("v_cvt_pk_bf16_f32 %0, %1, %2" : "=v"(r0[a]) : "v"(s[4 * a]), "v"(s[4 * a + 1]));
      asm("v_cvt_pk_bf16_f32 %0, %1, %2" : "=v"(r1[a]) : "v"(s[4 * a + 2]), "v"(s[4 * a + 3]));
    }
    short8 pa[2];
#pragma unroll
    for (int ksl = 0; ksl < 2; ++ksl) {
      uint32x2 w0 = __builtin_amdgcn_permlane32_swap(r0[2 * ksl], r0[2 * ksl + 1], false, false);
      uint32x2 w1 = __builtin_amdgcn_permlane32_swap(r1[2 * ksl], r1[2 * ksl + 1], false, false);
      union { short8 s8; uint32_t u[4]; } pk;
      pk.u[0] = w0[0]; pk.u[1] = w1[0]; pk.u[2] = w0[1]; pk.u[3] = w1[1];
      pa[ksl] = pk.s8;
    }

    // PV: oacc[n] += P * V   (V packed two d-rows per 128B LDS row)
    __builtin_amdgcn_s_setprio(1);
#pragma unroll
    for (int n = 0; n < 2; ++n)
#pragma unroll
      for (int ks = 0; ks < 2; ++ks) {
        int d = n * 32 + lm;
        int row = d >> 1;
        int o16p = (d & 1) * 4 + ks * 2 + h;
        int cb = ((o16p ^ (row & 7)) << 4);
        short8 vf = *reinterpret_cast<const short8*>(
            (const char*)Vlds + buf * 4096 + row * 128 + cb);
        oacc[n] = __builtin_amdgcn_mfma_f32_32x32x16_bf16(pa[ks], vf, oacc[n], 0, 0, 0);
      }
    __builtin_amdgcn_s_setprio(0);

    __syncthreads();
  }

  // epilogue: normalize by local l, store bf16 partial + (m, l)
  bcs[wave][lm] = __builtin_amdgcn_rcpf(lrun);
  f32x16 lv;
#pragma unroll
  for (int a = 0; a < 4; ++a) {
    f32x4 sv = *reinterpret_cast<const f32x4*>(&bcs[wave][a * 8 + h * 4]);
#pragma unroll
    for (int i = 0; i < 4; ++i) lv[a * 4 + i] = sv[i];
  }
  unsigned short* ob = opart + ((size_t)(sp * NH + head) * SEQ + q0) * 64;
#pragma unroll
  for (int n = 0; n < 2; ++n)
#pragma unroll
    for (int r = 0; r < 16; ++r) {
      int crow = (r & 3) + 8 * (r >> 2) + 4 * h;
      ob[crow * 64 + n * 32 + lm] = f2bf(oacc[n][r] * lv[r]);
    }
  if (h == 0) {
    mpart[(size_t)(sp * NH + head) * SEQ + q0 + lm] = mrun;
    lpart[(size_t)(sp * NH + head) * SEQ + q0 + lm] = lrun;
  }
}

// ---------- merge the four KV-splits (bf16 normalized partials) ----------
__global__ void merge_kernel(const unsigned short* __restrict__ opart,
                             const float* __restrict__ mpart,
                             const float* __restrict__ lpart,
                             unsigned short* __restrict__ Ab) {
  int tid = blockIdx.x * 256 + threadIdx.x;   // 786432 total
  int dv = tid & 15;
  int rq = tid >> 4;
  int head = rq >> 12;
  int q = rq & 4095;
  size_t base = (size_t)head * SEQ + q;
  const size_t str = (size_t)NH * SEQ;

  float m[NSP], l[NSP];
#pragma unroll
  for (int sp = 0; sp < NSP; ++sp) {
    m[sp] = mpart[base + sp * str];
    l[sp] = lpart[base + sp * str];
  }
  float mx = fmaxf(fmaxf(m[0], m[1]), fmaxf(m[2], m[3]));
  float w[NSP], denom = 0.f;
#pragma unroll
  for (int sp = 0; sp < NSP; ++sp) {
    w[sp] = __builtin_amdgcn_exp2f(m[sp] - mx) * l[sp];
    denom += w[sp];
  }
  float rd = 1.0f / denom;

  float acc0 = 0.f, acc1 = 0.f, acc2 = 0.f, acc3 = 0.f;
#pragma unroll
  for (int sp = 0; sp < NSP; ++sp) {
    float c = w[sp] * rd;
    ushort4 ov = *reinterpret_cast<const ushort4*>(
        opart + (base + sp * str) * 64 + dv * 4);
    acc0 += c * bf2f(ov.x);
    acc1 += c * bf2f(ov.y);
    acc2 += c * bf2f(ov.z);
    acc3 += c * bf2f(ov.w);
  }
  ushort4 r;
  r.x = f2bf(acc0); r.y = f2bf(acc1); r.z = f2bf(acc2); r.w = f2bf(acc3);
  *reinterpret_cast<ushort4*>(Ab + (size_t)q * EMB + head * DH + dv * 4) = r;
}

// ---------- launch ----------
extern "C" void kernel_launch(void* const* d_in, const int* in_sizes, int n_in,
                              void* d_out, int out_size, void* d_ws, size_t ws_size,
                              hipStream_t stream) {
  const float* x    = (const float*)d_in[0];
  const float* mask = (const float*)d_in[1];
  const float* Wq   = (const float*)d_in[2];
  const float* bq   = (const float*)d_in[3];
  const float* Wk   = (const float*)d_in[4];
  const float* bk   = (const float*)d_in[5];
  const float* Wv   = (const float*)d_in[6];
  const float* bv   = (const float*)d_in[7];
  const float* Wo   = (const float*)d_in[8];
  const float* bo   = (const float*)d_in[9];
  float* out = (float*)d_out;

  char* ws = (char*)d_ws;
  const size_t SZ_X = (size_t)SEQ * EMB * 2;
  const size_t SZ_W = (size_t)EMB * EMB * 2;
  unsigned short* xb  = (unsigned short*)(ws);
  unsigned short* wqb = (unsigned short*)(ws + SZ_X);
  unsigned short* wkb = (unsigned short*)(ws + SZ_X + SZ_W);
  unsigned short* wvb = (unsigned short*)(ws + SZ_X + 2 * SZ_W);
  unsigned short* wob = (unsigned short*)(ws + SZ_X + 3 * SZ_W);
  unsigned short* Qb  = (unsigned short*)(ws + SZ_X + 4 * SZ_W);
  unsigned short* Kbuf= (unsigned short*)(ws + 2 * SZ_X + 4 * SZ_W);
  unsigned short* Vb  = (unsigned short*)(ws + 3 * SZ_X + 4 * SZ_W);
  unsigned short* Vtb = (unsigned short*)(ws + 4 * SZ_X + 4 * SZ_W);
  unsigned short* Ab  = (unsigned short*)(ws + 5 * SZ_X + 4 * SZ_W);
  size_t off = 6 * SZ_X + 4 * SZ_W;
  float* mb2            = (float*)(ws + off);          off += (size_t)SEQ * 4;
  unsigned short* opart = (unsigned short*)(ws + off); off += (size_t)NSP * NH * SEQ * 64 * 2;
  float* mpart          = (float*)(ws + off);          off += (size_t)NSP * NH * SEQ * 4;
  float* lpart          = (float*)(ws + off);

  prep_kernel<<<dim3(192, 6), 256, 0, stream>>>(
      x, mask, Wq, Wk, Wv, Wo, xb, wqb, wkb, wvb, wob, mb2);

  qkv_gemm<<<dim3(SEQ / 128, EMB / 128, 3), 256, 0, stream>>>(
      xb, wqb, wkb, wvb, bq, bk, bv, Qb, Kbuf, Vb);

  transpose_kernel<<<dim3(EMB / 32, SEQ / 32), dim3(32, 8), 0, stream>>>(Vb, Vtb);

  attn_kernel<<<NBLK, 256, 0, stream>>>(Qb, Kbuf, Vtb, mb2, opart, mpart, lpart);
  merge_kernel<<<3072, 256, 0, stream>>>(opart, mpart, lpart, Ab);

  gemm_wo<<<dim3(SEQ / 128, EMB / 128), 256, 0, stream>>>(Ab, wob, bo, out);
}

// Round 14
// 127.655 us; speedup vs baseline: 1.3175x; 1.1198x over previous
//
#include <hip/hip_runtime.h>
#include <stdint.h>
#include <stddef.h>

#define EMB 768
#define SEQ 4096
#define NH 12
#define DH 64
#define LOG2E 1.44269504f
#define NSP 2
#define SPLEN (SEQ / NSP)            // 2048 kv per split
#define NBLK (NH * 32 * NSP)         // 768 blocks: 12 heads x 32 qtiles(128) x 2 splits

typedef __attribute__((ext_vector_type(8))) short short8;
typedef __attribute__((ext_vector_type(4))) float f32x4;
typedef __attribute__((ext_vector_type(16))) float f32x16;
typedef __attribute__((ext_vector_type(2))) unsigned int uint32x2;

// ---------- helpers ----------
static __device__ __forceinline__ unsigned short f2bf(float f) {
  union { float f; uint32_t u; } v; v.f = f;
  uint32_t u = v.u;
  return (unsigned short)((u + 0x7FFFu + ((u >> 16) & 1u)) >> 16);
}
static __device__ __forceinline__ float bf2f(unsigned short s) {
  union { uint32_t u; float f; } v; v.u = ((uint32_t)s) << 16;
  return v.f;
}

static __device__ __forceinline__ void gl_lds16(const void* g, void* l) {
  __builtin_amdgcn_global_load_lds(
      (const __attribute__((address_space(1))) uint32_t*)g,
      (__attribute__((address_space(3))) uint32_t*)l, 16, 0, 0);
}
static __device__ __forceinline__ void gl_lds4(const void* g, void* l) {
  __builtin_amdgcn_global_load_lds(
      (const __attribute__((address_space(1))) uint32_t*)g,
      (__attribute__((address_space(3))) uint32_t*)l, 4, 0, 0);
}

// cross-half combine via the permlane32_swap BUILTIN (asm with duplicated
// "+v" operands coalesces registers -> degenerate swap; round-4 failure).
static __device__ __forceinline__ float xhalf_max(float v) {
  union { float f; unsigned int u; } x; x.f = v;
  uint32x2 r = __builtin_amdgcn_permlane32_swap(x.u, x.u, false, false);
  union { unsigned int u; float f; } a, b; a.u = r[0]; b.u = r[1];
  return fmaxf(a.f, b.f);
}

// ---------- fused prep: fp32->bf16 of x + 4 weights, and mask bias ----------
// mb2 = -80000 * (1 - mask) == (exp2-domain additive bias) / sc2; attn
// C-initializes the QK accumulator with it; scale is folded into the exp fma.
__global__ void prep_kernel(const float* __restrict__ x, const float* __restrict__ mask,
                            const float* __restrict__ Wq, const float* __restrict__ Wk,
                            const float* __restrict__ Wv, const float* __restrict__ Wo,
                            unsigned short* __restrict__ xb, unsigned short* __restrict__ wqb,
                            unsigned short* __restrict__ wkb, unsigned short* __restrict__ wvb,
                            unsigned short* __restrict__ wob, float* __restrict__ mb2) {
  const int y = blockIdx.y;
  if (y == 5) {
    int i = blockIdx.x * 256 + threadIdx.x;
    if (i < SEQ) mb2[i] = -80000.f * (1.f - mask[i]);
    return;
  }
  const float* in = y == 0 ? x : y == 1 ? Wq : y == 2 ? Wk : y == 3 ? Wv : Wo;
  unsigned short* out = y == 0 ? xb : y == 1 ? wqb : y == 2 ? wkb : y == 3 ? wvb : wob;
  const int n = (y == 0) ? SEQ * EMB : EMB * EMB;
  int stride = gridDim.x * blockDim.x * 4;
  for (int i = (blockIdx.x * blockDim.x + threadIdx.x) * 4; i < n; i += stride) {
    float4 v = *reinterpret_cast<const float4*>(in + i);
    ushort4 o;
    o.x = f2bf(v.x); o.y = f2bf(v.y); o.z = f2bf(v.z); o.w = f2bf(v.w);
    *reinterpret_cast<ushort4*>(out + i) = o;
  }
}

// ---------- GEMM core: C[M][N] = A[M][K] * W[N][K]^T + bias ----------
template <int OUT_F32>
static __device__ __forceinline__ void gemm128(
    const unsigned short* __restrict__ A, const unsigned short* __restrict__ W,
    const float* __restrict__ bias, void* __restrict__ Cout,
    int M, int N, int K, int bm, int bn) {
  __shared__ unsigned short Alds[128 * 64];
  __shared__ unsigned short Blds[128 * 64];
  const int t = threadIdx.x;
  const int lane = t & 63;
  const int wave = t >> 6;
  const int wr = wave >> 1, wc = wave & 1;
  const int lm = lane & 15, lg = lane >> 4;

  f32x4 acc[4][4];
#pragma unroll
  for (int i = 0; i < 4; ++i)
#pragma unroll
    for (int j = 0; j < 4; ++j) acc[i][j] = (f32x4){0.f, 0.f, 0.f, 0.f};

  const int srow = t >> 3;
  const int scsw = (t & 7) * 16;

  const int nK = K >> 6;
  for (int kt = 0; kt < nK; ++kt) {
    const int k0 = kt << 6;
#pragma unroll
    for (int i = 0; i < 4; ++i) {
      int row = i * 32 + srow;
      int cb = scsw ^ ((row & 7) << 4);
      gl_lds16(A + (size_t)(bm * 128 + row) * K + k0 + (cb >> 1),
               (char*)Alds + i * 4096 + t * 16);
      gl_lds16(W + (size_t)(bn * 128 + row) * K + k0 + (cb >> 1),
               (char*)Blds + i * 4096 + t * 16);
    }
    __syncthreads();
#pragma unroll
    for (int kk = 0; kk < 2; ++kk) {
      short8 af[4], bfr[4];
#pragma unroll
      for (int i = 0; i < 4; ++i) {
        int rowa = wr * 64 + i * 16 + lm;
        int cba = (kk * 64 + lg * 16) ^ ((rowa & 7) << 4);
        af[i] = *reinterpret_cast<const short8*>((const char*)Alds + rowa * 128 + cba);
        int rowb = wc * 64 + i * 16 + lm;
        int cbb = (kk * 64 + lg * 16) ^ ((rowb & 7) << 4);
        bfr[i] = *reinterpret_cast<const short8*>((const char*)Blds + rowb * 128 + cbb);
      }
#pragma unroll
      for (int i = 0; i < 4; ++i)
#pragma unroll
        for (int j = 0; j < 4; ++j)
          acc[i][j] = __builtin_amdgcn_mfma_f32_16x16x32_bf16(af[i], bfr[j], acc[i][j], 0, 0, 0);
    }
    __syncthreads();
  }
#pragma unroll
  for (int i = 0; i < 4; ++i) {
    int row0 = bm * 128 + wr * 64 + i * 16 + lg * 4;
#pragma unroll
    for (int j = 0; j < 4; ++j) {
      int col = bn * 128 + wc * 64 + j * 16 + lm;
      float b = bias[col];
#pragma unroll
      for (int r = 0; r < 4; ++r) {
        float v = acc[i][j][r] + b;
        if (OUT_F32)
          ((float*)Cout)[(size_t)(row0 + r) * N + col] = v;
        else
          ((unsigned short*)Cout)[(size_t)(row0 + r) * N + col] = f2bf(v);
      }
    }
  }
}

__global__ __launch_bounds__(256, 2) void gemm_wo(
    const unsigned short* __restrict__ A, const unsigned short* __restrict__ W,
    const float* __restrict__ bias, float* __restrict__ C) {
  gemm128<1>(A, W, bias, C, SEQ, EMB, EMB, blockIdx.x, blockIdx.y);
}

__global__ __launch_bounds__(256, 2) void qkv_gemm(
    const unsigned short* __restrict__ A,
    const unsigned short* __restrict__ W0, const unsigned short* __restrict__ W1,
    const unsigned short* __restrict__ W2,
    const float* __restrict__ b0, const float* __restrict__ b1, const float* __restrict__ b2,
    unsigned short* __restrict__ O0, unsigned short* __restrict__ O1,
    unsigned short* __restrict__ O2) {
  const int z = blockIdx.z;
  const unsigned short* W = z == 0 ? W0 : z == 1 ? W1 : W2;
  const float* bias = z == 0 ? b0 : z == 1 ? b1 : b2;
  unsigned short* O = z == 0 ? O0 : z == 1 ? O1 : O2;
  gemm128<0>(A, W, bias, O, SEQ, EMB, EMB, blockIdx.x, blockIdx.y);
}

// ---------- V transpose: V[SEQ][EMB] -> Vt[EMB][SEQ] (bf16) ----------
__global__ void transpose_kernel(const unsigned short* __restrict__ in,
                                 unsigned short* __restrict__ out) {
  __shared__ unsigned short tile[32][33];
  int tx = threadIdx.x, ty = threadIdx.y;   // 32 x 8
  int e0 = blockIdx.x * 32, s0 = blockIdx.y * 32;
#pragma unroll
  for (int i = 0; i < 4; ++i)
    tile[ty + i * 8][tx] = in[(size_t)(s0 + ty + i * 8) * EMB + e0 + tx];
  __syncthreads();
#pragma unroll
  for (int i = 0; i < 4; ++i)
    out[(size_t)(e0 + ty + i * 8) * SEQ + s0 + tx] = tile[tx][ty + i * 8];
}

// ---------- flash attention: split-2, KVB=64, VALU-slimmed softmax ----------
// 768 blocks = 12 heads x 32 qtiles(128) x 2 halves = exactly 3 blocks/CU.
// VALU cuts vs round 9: (a) scale folded into exp fma (max computed on raw
// scores, commutes with positive scale); (b) row-sum l computed by 4 extra
// MFMAs with B=ones (bf16 P rowsum, C-layout matches oacc -> no broadcast);
// (c) max3-shaped reduction tree; (d) bf16 partial store.
__global__ __launch_bounds__(256, 3) void attn_kernel(
    const unsigned short* __restrict__ Q, const unsigned short* __restrict__ Kb,
    const unsigned short* __restrict__ Vt, const float* __restrict__ mb2,
    unsigned short* __restrict__ opart, float* __restrict__ mpart,
    float* __restrict__ lpart) {
  __shared__ unsigned short Klds[2][64 * DH];   // [kv][d] 128B rows, swz (row&7)<<4
  __shared__ unsigned short Vlds[2][DH * 64];   // [d][kv] 128B rows, swz (row&7)<<4
  __shared__ __align__(16) float msk[2][64];
  __shared__ __align__(16) float bcs[4][32];

  const int t = threadIdx.x;
  const int lane = t & 63;
  const int wave = t >> 6;
  const int o = blockIdx.x;
  const int wg = (o & 7) * (NBLK / 8) + (o >> 3);  // bijective: 768 % 8 == 0
  const int head = wg >> 6;                        // 64 blocks per head
  const int rem = wg & 63;
  const int qb = rem >> 1;                         // q-tile of 128 rows
  const int sp = rem & 1;
  const int q0 = qb * 128 + wave * 32;
  const int kvb0 = sp * SPLEN;
  const int lm = lane & 31;
  const int h = lane >> 5;

  // Q B-fragments (col = q = lm, k-octet = d = 16ks + 8h .. +8)
  short8 qf[4];
#pragma unroll
  for (int ks = 0; ks < 4; ++ks)
    qf[ks] = *reinterpret_cast<const short8*>(
        Q + (size_t)(q0 + lm) * EMB + head * DH + ks * 16 + h * 8);

  // all-ones bf16 B-fragment for the l = P*1 row-sum MFMA
  short8 ones;
#pragma unroll
  for (int i = 0; i < 8; ++i) ones[i] = (short)0x3F80;

  f32x16 oacc[2], lacc;
#pragma unroll
  for (int n = 0; n < 2; ++n)
#pragma unroll
    for (int r = 0; r < 16; ++r) oacc[n][r] = 0.f;
#pragma unroll
  for (int r = 0; r < 16; ++r) lacc[r] = 0.f;
  float mrun = -3.0e38f;

  const int srow = t >> 3;          // 0..31
  const int scol = (t & 7) * 16;    // byte col

  // 5 vmem ops per wave per STAGE: 2x K + 2x V gl_lds16 + 1x mask gl_lds4
  auto STAGE = [&](int buf, int kt2) {
    const int kv0 = kvb0 + kt2 * 64;
#pragma unroll
    for (int i = 0; i < 2; ++i) {
      int row = i * 32 + srow;
      int cb = scol ^ ((row & 7) << 4);
      gl_lds16(Kb + (size_t)(kv0 + row) * EMB + head * DH + (cb >> 1),
               (char*)Klds + buf * 8192 + i * 4096 + t * 16);
      gl_lds16(Vt + (size_t)(head * DH + row) * SEQ + kv0 + (cb >> 1),
               (char*)Vlds + buf * 8192 + i * 4096 + t * 16);
    }
    gl_lds4(mb2 + kv0 + lane, &msk[buf][0]);   // all 4 waves dup: benign
  };

  constexpr int NT = SPLEN / 64;   // 32
  STAGE(0, 0);
  __syncthreads();

  const float sc2 = 0.125f * LOG2E;

  for (int kt = 0; kt < NT; ++kt) {
    const int buf = kt & 1;
    if (kt + 1 < NT) STAGE(buf ^ 1, kt + 1);

    // QK^T swapped: C[kv][q]; ACC INIT = mask bias / sc2 (from staged LDS)
    f32x16 s[2];
#pragma unroll
    for (int tt = 0; tt < 2; ++tt)
#pragma unroll
      for (int a = 0; a < 4; ++a) {
        f32x4 m = *reinterpret_cast<const f32x4*>(&msk[buf][tt * 32 + a * 8 + h * 4]);
#pragma unroll
        for (int i = 0; i < 4; ++i) s[tt][a * 4 + i] = m[i];
      }

    __builtin_amdgcn_s_setprio(1);
#pragma unroll
    for (int tt = 0; tt < 2; ++tt)
#pragma unroll
      for (int ks = 0; ks < 4; ++ks) {
        int row = tt * 32 + lm;
        int cb = (ks * 32 + h * 16) ^ ((row & 7) << 4);
        short8 kf = *reinterpret_cast<const short8*>(
            (const char*)Klds + buf * 8192 + row * 128 + cb);
        s[tt] = __builtin_amdgcn_mfma_f32_32x32x16_bf16(kf, qf[ks], s[tt], 0, 0, 0);
      }
    __builtin_amdgcn_s_setprio(0);

    // row max over the 32 RAW values (max commutes with positive scale):
    // max3-shaped tree, 16 ops, then cross-half + single scale mul.
    float red[8];
#pragma unroll
    for (int r = 0; r < 8; ++r)
      red[r] = fmaxf(fmaxf(s[0][r], s[0][r + 8]), s[1][r]);
#pragma unroll
    for (int r = 0; r < 4; ++r)
      red[r] = fmaxf(fmaxf(red[r], red[r + 4]), s[1][8 + r]);
#pragma unroll
    for (int r = 0; r < 2; ++r)
      red[r] = fmaxf(fmaxf(red[r], red[r + 2]), s[1][12 + r]);
    red[0] = fmaxf(fmaxf(red[0], red[1]), s[1][14]);
    red[0] = fmaxf(red[0], s[1][15]);
    float pm = xhalf_max(red[0]) * sc2;

    // defer-max: rescale O (and l) only when max grows past threshold
    if (!__all(pm <= mrun + 8.0f)) {
      float mnew = fmaxf(mrun, pm);
      float sf = __builtin_amdgcn_exp2f(mrun - mnew);
      mrun = mnew;
      bcs[wave][lm] = sf;
      f32x16 svv;
#pragma unroll
      for (int a = 0; a < 4; ++a) {
        f32x4 sv = *reinterpret_cast<const f32x4*>(&bcs[wave][a * 8 + h * 4]);
#pragma unroll
        for (int i = 0; i < 4; ++i) svv[a * 4 + i] = sv[i];
      }
      oacc[0] = oacc[0] * svv;
      oacc[1] = oacc[1] * svv;
      lacc = lacc * svv;
    }

    // P = exp2(s_raw * sc2 - m): one fma + one exp per element
#pragma unroll
    for (int tt = 0; tt < 2; ++tt)
#pragma unroll
      for (int r = 0; r < 16; ++r)
        s[tt][r] = __builtin_amdgcn_exp2f(fmaf(s[tt][r], sc2, -mrun));

    // P -> bf16 A-fragments (T12: cvt_pk + permlane32_swap)
    short8 pa[4];
#pragma unroll
    for (int tt = 0; tt < 2; ++tt) {
      uint32_t r0[4], r1[4];
#pragma unroll
      for (int a = 0; a < 4; ++a) {
        asm("v_cvt_pk_bf16_f32 %0, %1, %2" : "=v"(r0[a]) : "v"(s[tt][4 * a]), "v"(s[tt][4 * a + 1]));
        asm("v_cvt_pk_bf16_f32 %0, %1, %2" : "=v"(r1[a]) : "v"(s[tt][4 * a + 2]), "v"(s[tt][4 * a + 3]));
      }
#pragma unroll
      for (int ksl = 0; ksl < 2; ++ksl) {
        uint32x2 w0 = __builtin_amdgcn_permlane32_swap(r0[2 * ksl], r0[2 * ksl + 1], false, false);
        uint32x2 w1 = __builtin_amdgcn_permlane32_swap(r1[2 * ksl], r1[2 * ksl + 1], false, false);
        union { short8 s8; uint32_t u[4]; } pk;
        pk.u[0] = w0[0]; pk.u[1] = w1[0]; pk.u[2] = w0[1]; pk.u[3] = w1[1];
        pa[tt * 2 + ksl] = pk.s8;
      }
    }

    // PV: oacc[n] += P * V ; lacc += P * 1 (row-sum on the matrix pipe)
    __builtin_amdgcn_s_setprio(1);
#pragma unroll
    for (int n = 0; n < 2; ++n)
#pragma unroll
      for (int ks = 0; ks < 4; ++ks) {
        int row = n * 32 + lm;
        int cb = (ks * 32 + h * 16) ^ ((row & 7) << 4);
        short8 vf = *reinterpret_cast<const short8*>(
            (const char*)Vlds + buf * 8192 + row * 128 + cb);
        oacc[n] = __builtin_amdgcn_mfma_f32_32x32x16_bf16(pa[ks], vf, oacc[n], 0, 0, 0);
      }
#pragma unroll
    for (int ks = 0; ks < 4; ++ks)
      lacc = __builtin_amdgcn_mfma_f32_32x32x16_bf16(pa[ks], ones, lacc, 0, 0, 0);
    __builtin_amdgcn_s_setprio(0);

    __syncthreads();
  }

  // epilogue: lacc is already per-q in C-layout -> direct normalize, bf16 out
  f32x16 rl;
#pragma unroll
  for (int r = 0; r < 16; ++r) rl[r] = __builtin_amdgcn_rcpf(lacc[r]);
  unsigned short* ob = opart + ((size_t)(sp * NH + head) * SEQ + q0) * 64;
#pragma unroll
  for (int n = 0; n < 2; ++n)
#pragma unroll
    for (int r = 0; r < 16; ++r) {
      int crow = (r & 3) + 8 * (r >> 2) + 4 * h;
      ob[crow * 64 + n * 32 + lm] = f2bf(oacc[n][r] * rl[r]);
    }
  const size_t pbase = (size_t)(sp * NH + head) * SEQ + q0;
  if (h == 0) mpart[pbase + lm] = mrun;
  if (lm == 0) {
#pragma unroll
    for (int r = 0; r < 16; ++r) {
      int crow = (r & 3) + 8 * (r >> 2) + 4 * h;
      lpart[pbase + crow] = lacc[r];
    }
  }
}

// ---------- merge the two KV-halves (bf16 normalized partials) ----------
__global__ void merge_kernel(const unsigned short* __restrict__ opart,
                             const float* __restrict__ mpart,
                             const float* __restrict__ lpart,
                             unsigned short* __restrict__ Ab) {
  int tid = blockIdx.x * 256 + threadIdx.x;   // 786432 total
  int dv = tid & 15;
  int rq = tid >> 4;
  int head = rq >> 12;
  int q = rq & 4095;
  size_t base = (size_t)head * SEQ + q;
  const size_t str = (size_t)NH * SEQ;

  float m0 = mpart[base], m1 = mpart[base + str];
  float l0 = lpart[base], l1 = lpart[base + str];
  float mx = fmaxf(m0, m1);
  float w0 = __builtin_amdgcn_exp2f(m0 - mx) * l0;
  float w1 = __builtin_amdgcn_exp2f(m1 - mx) * l1;
  float rd = 1.0f / (w0 + w1);
  float c0 = w0 * rd, c1 = w1 * rd;

  ushort4 o0 = *reinterpret_cast<const ushort4*>(opart + base * 64 + dv * 4);
  ushort4 o1 = *reinterpret_cast<const ushort4*>(opart + (base + str) * 64 + dv * 4);
  ushort4 r;
  r.x = f2bf(c0 * bf2f(o0.x) + c1 * bf2f(o1.x));
  r.y = f2bf(c0 * bf2f(o0.y) + c1 * bf2f(o1.y));
  r.z = f2bf(c0 * bf2f(o0.z) + c1 * bf2f(o1.z));
  r.w = f2bf(c0 * bf2f(o0.w) + c1 * bf2f(o1.w));
  *reinterpret_cast<ushort4*>(Ab + (size_t)q * EMB + head * DH + dv * 4) = r;
}

// ---------- launch ----------
extern "C" void kernel_launch(void* const* d_in, const int* in_sizes, int n_in,
                              void* d_out, int out_size, void* d_ws, size_t ws_size,
                              hipStream_t stream) {
  const float* x    = (const float*)d_in[0];
  const float* mask = (const float*)d_in[1];
  const float* Wq   = (const float*)d_in[2];
  const float* bq   = (const float*)d_in[3];
  const float* Wk   = (const float*)d_in[4];
  const float* bk   = (const float*)d_in[5];
  const float* Wv   = (const float*)d_in[6];
  const float* bv   = (const float*)d_in[7];
  const float* Wo   = (const float*)d_in[8];
  const float* bo   = (const float*)d_in[9];
  float* out = (float*)d_out;

  char* ws = (char*)d_ws;
  const size_t SZ_X = (size_t)SEQ * EMB * 2;
  const size_t SZ_W = (size_t)EMB * EMB * 2;
  unsigned short* xb  = (unsigned short*)(ws);
  unsigned short* wqb = (unsigned short*)(ws + SZ_X);
  unsigned short* wkb = (unsigned short*)(ws + SZ_X + SZ_W);
  unsigned short* wvb = (unsigned short*)(ws + SZ_X + 2 * SZ_W);
  unsigned short* wob = (unsigned short*)(ws + SZ_X + 3 * SZ_W);
  unsigned short* Qb  = (unsigned short*)(ws + SZ_X + 4 * SZ_W);
  unsigned short* Kbuf= (unsigned short*)(ws + 2 * SZ_X + 4 * SZ_W);
  unsigned short* Vb  = (unsigned short*)(ws + 3 * SZ_X + 4 * SZ_W);
  unsigned short* Vtb = (unsigned short*)(ws + 4 * SZ_X + 4 * SZ_W);
  unsigned short* Ab  = (unsigned short*)(ws + 5 * SZ_X + 4 * SZ_W);
  size_t off = 6 * SZ_X + 4 * SZ_W;
  float* mb2            = (float*)(ws + off);          off += (size_t)SEQ * 4;
  unsigned short* opart = (unsigned short*)(ws + off); off += (size_t)NSP * NH * SEQ * 64 * 2;
  float* mpart          = (float*)(ws + off);          off += (size_t)NSP * NH * SEQ * 4;
  float* lpart          = (float*)(ws + off);

  prep_kernel<<<dim3(192, 6), 256, 0, stream>>>(
      x, mask, Wq, Wk, Wv, Wo, xb, wqb, wkb, wvb, wob, mb2);

  qkv_gemm<<<dim3(SEQ / 128, EMB / 128, 3), 256, 0, stream>>>(
      xb, wqb, wkb, wvb, bq, bk, bv, Qb, Kbuf, Vb);

  transpose_kernel<<<dim3(EMB / 32, SEQ / 32), dim3(32, 8), 0, stream>>>(Vb, Vtb);

  attn_kernel<<<NBLK, 256, 0, stream>>>(Qb, Kbuf, Vtb, mb2, opart, mpart, lpart);
  merge_kernel<<<3072, 256, 0, stream>>>(opart, mpart, lpart, Ab);

  gemm_wo<<<dim3(SEQ / 128, EMB / 128), 256, 0, stream>>>(Ab, wob, bo, out);
}